// Round 5
// baseline (45.718 us; speedup 1.0000x reference)
//
#include <hip/hip_runtime.h>
#include <hip/hip_fp16.h>
#include <stdint.h>

#define W_ 512
#define H_ 512
#define HW_ (512 * 512)
#define RMAX 4          // slot capacity/pixel: one 64B line; k>4 handled exactly via overflow
#define OVF_CAP 65536
#define PXB 2048        // pixels per composite block
#define CTHR 256

// ---- projection: exact replica of the reference f32 arithmetic ----
__device__ __forceinline__ int project_pix(float x, float y, float z) {
    float zz = z + 1e-6f;
    float xf = x / zz * 512.0f + 256.0f;
    float yf = y / zz * 512.0f + 256.0f;
    xf = fminf(fmaxf(xf, -1e9f), 1e9f);
    yf = fminf(fmaxf(yf, -1e9f), 1e9f);
    int xi = (int)xf;   // trunc toward zero
    int yi = (int)yf;
    if (xi >= 0 && xi < W_ && yi >= 0 && yi < H_) return yi * W_ + xi;
    return -1;
}

__device__ __forceinline__ float lo_h(unsigned int u) {
    return __half2float(__ushort_as_half((unsigned short)(u & 0xffffu)));
}
__device__ __forceinline__ float hi_h(unsigned int u) {
    return __half2float(__ushort_as_half((unsigned short)(u >> 16)));
}

// ---- pass 0: zero cnt16 + overflow header ----
__global__ void __launch_bounds__(256) k_init(uint4* __restrict__ p, int n4) {
    int i = blockIdx.x * blockDim.x + threadIdx.x;
    if (i < n4) p[i] = make_uint4(0u, 0u, 0u, 0u);
}

// ---- pass 1: single-pass build of per-pixel slot arrays ----
// cnt: u16 per pixel packed in u32 pairs.
// record: .x = z bits, .y = global idx, .z = f16(o)|f16(r)<<16, .w = f16(g)|f16(b)<<16
__global__ void __launch_bounds__(256) k_build(const float4* __restrict__ xyz4,
                                               const float* __restrict__ op,
                                               const float* __restrict__ col,
                                               unsigned int* __restrict__ cnt,
                                               uint4* __restrict__ slots,
                                               unsigned int* __restrict__ ovf_hdr,
                                               unsigned int* __restrict__ ovf_pix,
                                               uint4* __restrict__ ovf_rec,
                                               int N, int total4) {
    int t = blockIdx.x * blockDim.x + threadIdx.x;
    if (t >= total4) return;
    float4 v0 = xyz4[3 * (size_t)t + 0];
    float4 v1 = xyz4[3 * (size_t)t + 1];
    float4 v2 = xyz4[3 * (size_t)t + 2];
    float xs[4] = {v0.x, v0.w, v1.z, v2.y};
    float ys[4] = {v0.y, v1.x, v1.w, v2.z};
    float zs[4] = {v0.z, v1.y, v2.x, v2.w};
    int g0 = 4 * t;
    size_t pbase = (size_t)(g0 / N) * HW_;   // 4 consecutive g share a batch (N%4==0)
#pragma unroll
    for (int j = 0; j < 4; ++j) {
        int pix = project_pix(xs[j], ys[j], zs[j]);
        if (pix >= 0) {
            int g = g0 + j;
            size_t p = pbase + pix;
            unsigned int sh = 16u * (unsigned int)(p & 1);
            unsigned int old = atomicAdd(&cnt[p >> 1], 1u << sh);
            unsigned int s = (old >> sh) & 0xffffu;
            // conditional (visible-only) gathers of opacity & color
            float o  = op[g];
            float cr = col[3 * (size_t)g + 0];
            float cg = col[3 * (size_t)g + 1];
            float cb = col[3 * (size_t)g + 2];
            uint4 rec;
            rec.x = __float_as_uint(zs[j]);
            rec.y = (unsigned int)g;
            rec.z = (unsigned int)__half_as_ushort(__float2half_rn(o)) |
                    ((unsigned int)__half_as_ushort(__float2half_rn(cr)) << 16);
            rec.w = (unsigned int)__half_as_ushort(__float2half_rn(cg)) |
                    ((unsigned int)__half_as_ushort(__float2half_rn(cb)) << 16);
            if (s < RMAX) {
                slots[p * RMAX + s] = rec;
            } else {
                unsigned int i = atomicAdd(ovf_hdr, 1u);
                if (i < OVF_CAP) { ovf_pix[i] = (unsigned int)p; ovf_rec[i] = rec; }
            }
        }
    }
}

// ---- pass 2: composite with in-block compaction ----
// Each block owns PXB consecutive pixels (same batch). Pass A: coalesced zero
// stores for all 4 output planes + push occupied pixel ids to LDS queue.
// Pass B: lanes process queue entries (~full lane utilization), overwrite.
__global__ void __launch_bounds__(CTHR) k_composite(const unsigned int* __restrict__ cnt,
                                                    const uint4* __restrict__ slots,
                                                    const unsigned int* __restrict__ ovf_hdr,
                                                    const unsigned int* __restrict__ ovf_pix,
                                                    const uint4* __restrict__ ovf_rec,
                                                    float* __restrict__ out, int B) {
    __shared__ unsigned int q[PXB];
    __shared__ unsigned int qn;
    int t = threadIdx.x;
    if (t == 0) qn = 0u;
    __syncthreads();

    int pb0 = blockIdx.x * PXB;
    int b = pb0 / HW_;          // PXB | HW_ -> whole block in one batch
    int pl0 = pb0 - b * HW_;
    size_t HWs = (size_t)HW_;
    float* oR = out + ((size_t)b * 3 + 0) * HWs;
    float* oG = out + ((size_t)b * 3 + 1) * HWs;
    float* oB = out + ((size_t)b * 3 + 2) * HWs;
    float* oD = out + (size_t)B * 3 * HWs + (size_t)b * HWs;

    // counts for my 8 pixels (u16 packed): one uint4
    uint4 cw = ((const uint4*)cnt)[(pb0 >> 3) + t];
    unsigned int ws[4] = {cw.x, cw.y, cw.z, cw.w};

    // zero defaults, coalesced
    int pz = pl0 + t * 8;
    float4 z4 = make_float4(0.f, 0.f, 0.f, 0.f);
    *(float4*)(oR + pz) = z4; *(float4*)(oR + pz + 4) = z4;
    *(float4*)(oG + pz) = z4; *(float4*)(oG + pz + 4) = z4;
    *(float4*)(oB + pz) = z4; *(float4*)(oB + pz + 4) = z4;
    *(float4*)(oD + pz) = z4; *(float4*)(oD + pz + 4) = z4;

    // push occupied pixels
#pragma unroll
    for (int j = 0; j < 8; ++j) {
        unsigned int k = (ws[j >> 1] >> (16 * (j & 1))) & 0xffffu;
        if (k) {
            unsigned int i = atomicAdd(&qn, 1u);
            q[i] = (k << 16) | (unsigned int)(t * 8 + j);
        }
    }
    __syncthreads();   // also drains the zero stores (vmcnt(0) before barrier)

    unsigned int n = qn;
    for (unsigned int i = t; i < n; i += CTHR) {
        unsigned int e = q[i];
        int k = (int)(e >> 16);
        int id = (int)(e & 0xffffu);
        size_t p = (size_t)pb0 + id;
        size_t sbase = p * RMAX;
        float r = 0.f, g2 = 0.f, bl = 0.f, depth = 0.f, T = 1.f;

        if (k <= RMAX) {
            float z_[RMAX];
            int   i_[RMAX];
            unsigned int pa_[RMAX], pb_[RMAX];
#pragma unroll
            for (int s = 0; s < RMAX; ++s) {
                if (s < k) {
                    uint4 rec = slots[sbase + s];
                    z_[s] = __uint_as_float(rec.x);
                    i_[s] = (int)rec.y;
                    pa_[s] = rec.z;
                    pb_[s] = rec.w;
                } else {
                    z_[s] = -__builtin_inff();
                    i_[s] = 0x7fffffff;
                    pa_[s] = 0u;
                    pb_[s] = 0u;
                }
            }
            // sort desc by z, ties asc by idx — 4-element network, 5 CEs, static idx
#define CE(I, J)                                                              \
            {                                                                 \
                bool sw = (z_[J] > z_[I]) || (z_[J] == z_[I] && i_[J] < i_[I]); \
                if (sw) {                                                     \
                    float tz = z_[I]; z_[I] = z_[J]; z_[J] = tz;              \
                    int ti = i_[I]; i_[I] = i_[J]; i_[J] = ti;                \
                    unsigned int ta = pa_[I]; pa_[I] = pa_[J]; pa_[J] = ta;   \
                    unsigned int tb = pb_[I]; pb_[I] = pb_[J]; pb_[J] = tb;   \
                }                                                             \
            }
            CE(0,1) CE(2,3) CE(0,2) CE(1,3) CE(1,2)
#undef CE
#pragma unroll
            for (int s = 0; s < RMAX; ++s) {
                if (s < k) {
                    float o  = lo_h(pa_[s]);
                    float rr = hi_h(pa_[s]);
                    float gg = lo_h(pb_[s]);
                    float bb = hi_h(pb_[s]);
                    float a = o * T;
                    r  += a * rr;
                    g2 += a * gg;
                    bl += a * bb;
                    T *= (1.0f - o);
                    depth = z_[s];   // last valid = min z = front-most
                }
            }
        } else {
            // cold exact path (k > RMAX, ~1 pixel/launch): slots + overflow union
            unsigned int nov = ovf_hdr[0];
            if (nov > OVF_CAP) nov = OVF_CAP;
            unsigned int ptag = (unsigned int)p;
            float prev_z = __builtin_inff();
            int prev_i = -1;
            for (int s = 0; s < k; ++s) {
                float best_z = -__builtin_inff();
                int best_i = 0x7fffffff;
                unsigned int ba = 0u, bb2 = 0u;
                for (int t2 = 0; t2 < RMAX; ++t2) {
                    uint4 rec = slots[sbase + t2];
                    float z = __uint_as_float(rec.x);
                    int   i2 = (int)rec.y;
                    bool after  = (z < prev_z) || (z == prev_z && i2 > prev_i);
                    bool better = (z > best_z) || (z == best_z && i2 < best_i);
                    if (after && better) { best_z = z; best_i = i2; ba = rec.z; bb2 = rec.w; }
                }
                for (unsigned int t2 = 0; t2 < nov; ++t2) {
                    if (ovf_pix[t2] == ptag) {
                        uint4 rec = ovf_rec[t2];
                        float z = __uint_as_float(rec.x);
                        int   i2 = (int)rec.y;
                        bool after  = (z < prev_z) || (z == prev_z && i2 > prev_i);
                        bool better = (z > best_z) || (z == best_z && i2 < best_i);
                        if (after && better) { best_z = z; best_i = i2; ba = rec.z; bb2 = rec.w; }
                    }
                }
                float o  = lo_h(ba);
                float rr = hi_h(ba);
                float gg = lo_h(bb2);
                float bb = hi_h(bb2);
                float a = o * T;
                r  += a * rr;
                g2 += a * gg;
                bl += a * bb;
                T *= (1.0f - o);
                depth = best_z;
                prev_z = best_z;
                prev_i = best_i;
            }
        }

        int pl = pl0 + id;
        oR[pl] = r;
        oG[pl] = g2;
        oB[pl] = bl;
        oD[pl] = depth;
    }
}

extern "C" void kernel_launch(void* const* d_in, const int* in_sizes, int n_in,
                              void* d_out, int out_size, void* d_ws, size_t ws_size,
                              hipStream_t stream) {
    const float* xyz     = (const float*)d_in[0];
    // d_in[1] = scale (unused), d_in[2] = rotation (unused)
    const float* opacity = (const float*)d_in[3];
    const float* color   = (const float*)d_in[4];
    float* out = (float*)d_out;

    int B = out_size / (4 * HW_);        // render (B,3,H,W) + depth (B,1,H,W)
    int N = in_sizes[0] / (3 * B);
    int total = B * N;
    int nb = B * HW_;

    // ws layout (u32 units): [cnt16: nb/2][ovf_hdr: 1024][ovf_pix: OVF_CAP]
    //                        [ovf_rec: OVF_CAP uint4][slots: nb*RMAX uint4]
    unsigned int* cnt     = (unsigned int*)d_ws;
    unsigned int* ovf_hdr = cnt + nb / 2;
    unsigned int* ovf_pix = ovf_hdr + 1024;
    uint4*        ovf_rec = (uint4*)(ovf_pix + OVF_CAP);
    uint4*        slots   = ovf_rec + OVF_CAP;
    // bytes: 4.2M + 4K + 0.26M + 4.2M + 134M ≈ 143MB

    int blk = 256;
    int zwords = nb / 2 + 1024;          // cnt16 + ovf_hdr
    int z4 = zwords / 4;
    k_init<<<(z4 + blk - 1) / blk, blk, 0, stream>>>((uint4*)cnt, z4);

    int total4 = total / 4;
    k_build<<<(total4 + blk - 1) / blk, blk, 0, stream>>>((const float4*)xyz,
                                                          opacity, color,
                                                          cnt, slots, ovf_hdr, ovf_pix, ovf_rec,
                                                          N, total4);

    int nblk = nb / PXB;
    k_composite<<<nblk, CTHR, 0, stream>>>(cnt, slots, ovf_hdr, ovf_pix, ovf_rec, out, B);
}